// Round 12
// baseline (2544.104 us; speedup 1.0000x reference)
//
#include <hip/hip_runtime.h>
#include <hip/hip_bf16.h>

#define D 128        // EMBED == LAYER == 128
#define BSHIFT 6     // 64 users per bucket
#define BUSERS (1 << BSHIFT)
#define NBLK 256     // blocks for hist/scatter passes
#define CHUNK 1280   // edges staged per bucket-chunk (avg bucket ~1024)
#define MROWS 64     // pw: item rows per block

typedef __attribute__((ext_vector_type(8))) short bf16x8;
typedef __attribute__((ext_vector_type(4))) float f32x4;

// round-to-nearest f32 -> bf16 bits
__device__ __forceinline__ unsigned int bf16rn(float f) {
  unsigned int u = __float_as_uint(f);
  return (u + 0x7fffu + ((u >> 16) & 1u)) >> 16;
}

// ---------------------------------------------------------------------------
// Kernel 1 (fused): blocks [0, npw) run the MFMA pw GEMM; blocks [npw,
// npw+NBLK) run the bucket histogram. Overlaps compute-heavy pw with
// BW-heavy hist and saves a launch gap. Shared LDS arena (48 KB).
// ---------------------------------------------------------------------------
__global__ __launch_bounds__(256) void pw_hist_kernel(
    const float* __restrict__ emb, const float* __restrict__ W,
    unsigned short* __restrict__ Pb, int n_items, int npw,
    const int* __restrict__ rows, int* __restrict__ bcount, int n_edges,
    int epb, int nbuck) {
  __shared__ __align__(16) char smem[49152];
  const int tid = threadIdx.x;

  if ((int)blockIdx.x < npw) {
    // ---------------- pw: P = item_emb @ W (MFMA bf16, verified r10) -------
    unsigned short* Wt = (unsigned short*)smem;            // 32 KB swizzled
    unsigned short* At = (unsigned short*)(smem + 32768);  // 16 KB swizzled
    const int m0 = blockIdx.x * MROWS;

    for (int i = tid; i < 128 * 128; i += 256) {
      const int k = i >> 7, c = i & 127;
      const unsigned short v = (unsigned short)bf16rn(W[i]);
      const int boff = c * 256 + ((2 * k) ^ ((c & 7) << 4));
      *reinterpret_cast<unsigned short*>(reinterpret_cast<char*>(Wt) + boff) = v;
    }
    for (int i = tid; i < MROWS * 128; i += 256) {
      const int r = i >> 7, k = i & 127;
      const int gr = m0 + r;
      const float f = (gr < n_items) ? emb[(size_t)gr * 128 + k] : 0.f;
      const unsigned short v = (unsigned short)bf16rn(f);
      const int boff = r * 256 + ((2 * k) ^ ((r & 7) << 4));
      *reinterpret_cast<unsigned short*>(reinterpret_cast<char*>(At) + boff) = v;
    }
    __syncthreads();

    const int w = tid >> 6;
    const int lane = tid & 63;
    const int lr = lane & 15;
    const int lg = lane >> 4;

    bf16x8 a[4];
    {
      const int rloc = w * 16 + lr;
#pragma unroll
      for (int ks = 0; ks < 4; ++ks) {
        const int boff = rloc * 256 + (((ks * 64) + lg * 16) ^ ((lr & 7) << 4));
        a[ks] = *reinterpret_cast<const bf16x8*>(
            reinterpret_cast<const char*>(At) + boff);
      }
    }

    f32x4 acc[8];
#pragma unroll
    for (int cs = 0; cs < 8; ++cs) acc[cs] = {0.f, 0.f, 0.f, 0.f};

#pragma unroll
    for (int cs = 0; cs < 8; ++cs) {
      const int c = cs * 16 + lr;
#pragma unroll
      for (int ks = 0; ks < 4; ++ks) {
        const int boff = c * 256 + (((ks * 64) + lg * 16) ^ ((lr & 7) << 4));
        const bf16x8 b = *reinterpret_cast<const bf16x8*>(
            reinterpret_cast<const char*>(Wt) + boff);
        acc[cs] = __builtin_amdgcn_mfma_f32_16x16x32_bf16(a[ks], b, acc[cs],
                                                          0, 0, 0);
      }
    }

#pragma unroll
    for (int cs = 0; cs < 8; ++cs) {
      const int c = cs * 16 + lr;
#pragma unroll
      for (int reg = 0; reg < 4; ++reg) {
        const int r = m0 + w * 16 + lg * 4 + reg;
        if (r < n_items)
          Pb[(size_t)r * 128 + c] = (unsigned short)bf16rn(acc[cs][reg]);
      }
    }
  } else {
    // ---------------- hist: per-block bucket histogram ---------------------
    int* h = (int*)smem;
    const int hb = blockIdx.x - npw;
    for (int b = tid; b < nbuck; b += 256) h[b] = 0;
    __syncthreads();
    const int e0 = hb * epb;
    const int e1 = (e0 + epb < n_edges) ? e0 + epb : n_edges;
    for (int e = e0 + tid; e < e1; e += 256)
      atomicAdd(&h[rows[e] >> BSHIFT], 1);
    __syncthreads();
    for (int b = tid; b < nbuck; b += 256)
      bcount[(size_t)b * NBLK + hb] = h[b];
  }
}

// ---------------------------------------------------------------------------
// Kernel 2: single-launch chained exclusive scan (release/acquire carry).
// All blocks co-resident (16 waves x 391 blocks = 6256 < 8192 capacity).
// ---------------------------------------------------------------------------
__global__ __launch_bounds__(1024) void chainscan_kernel(
    const int* __restrict__ in, int* __restrict__ base, int* __restrict__ carry,
    int* __restrict__ flag, int n) {
  __shared__ int lds[1024];
  __shared__ int sprev;
  const int tid = threadIdx.x;
  const int b = blockIdx.x;
  const int i = b * 1024 + tid;
  const int x = (i < n) ? in[i] : 0;
  lds[tid] = x;
  __syncthreads();
  for (int s = 1; s < 1024; s <<= 1) {
    const int y = (tid >= s) ? lds[tid - s] : 0;
    __syncthreads();
    lds[tid] += y;
    __syncthreads();
  }
  if (tid == 0) {
    int prev = 0;
    if (b > 0) {
      while (__hip_atomic_load(&flag[b - 1], __ATOMIC_ACQUIRE,
                               __HIP_MEMORY_SCOPE_AGENT) == 0) {}
      prev = carry[b - 1];
    }
    carry[b] = prev + lds[1023];
    __hip_atomic_store(&flag[b], 1, __ATOMIC_RELEASE,
                       __HIP_MEMORY_SCOPE_AGENT);
    sprev = prev;
  }
  __syncthreads();
  if (i < n) base[i] = sprev + lds[tid] - x;
}

// ---------------------------------------------------------------------------
// Kernel 3: scatter pass — LDS cursors seeded by scanned base.
// ---------------------------------------------------------------------------
__global__ __launch_bounds__(256) void scatter2_kernel(
    const int* __restrict__ rows, const int* __restrict__ cols,
    const float* __restrict__ vals, const int* __restrict__ base,
    int2* __restrict__ sedge, int n_edges, int epb, int nbuck) {
  __shared__ int cur[1600];
  const int tid = threadIdx.x;
  for (int b = tid; b < nbuck; b += 256)
    cur[b] = base[(size_t)b * NBLK + blockIdx.x];
  __syncthreads();
  const int e0 = blockIdx.x * epb;
  const int e1 = (e0 + epb < n_edges) ? e0 + epb : n_edges;
  for (int e = e0 + tid; e < e1; e += 256) {
    const int r = rows[e];
    const int pos = atomicAdd(&cur[r >> BSHIFT], 1);
    sedge[pos] =
        make_int2(((r & (BUSERS - 1)) << 16) | cols[e], __float_as_int(vals[e]));
  }
}

// ---------------------------------------------------------------------------
// Kernel 4: per-bucket LDS counting-sort + register accumulation.
// 256 threads = 8 half-waves x 8 users; 32 lanes own uint2 (4 bf16 cols).
// ---------------------------------------------------------------------------
__global__ __launch_bounds__(256) void bucket_gather_kernel(
    const uint2* __restrict__ Pb2,  // bf16 quads, 32 uint2 per row
    const int* __restrict__ base, const int2* __restrict__ sedge,
    const float* __restrict__ nj, float* __restrict__ out, int n_users,
    int n_edges, int nbuck) {
  __shared__ int2 eraw[CHUNK];    // 10 KB
  __shared__ int2 esort[CHUNK];   // 10 KB
  __shared__ int cnt[BUSERS];
  __shared__ int incl[BUSERS];

  const int tid = threadIdx.x;
  const int b = blockIdx.x;
  const int u0 = b << BSHIFT;
  const int hw = tid >> 5;        // half-wave 0..7
  const int lane = tid & 31;

  const int beg = base[(size_t)b * NBLK];
  const int end = (b + 1 < nbuck) ? base[(size_t)(b + 1) * NBLK] : n_edges;

  float4 acc[8];
#pragma unroll
  for (int k = 0; k < 8; ++k) acc[k] = {0.f, 0.f, 0.f, 0.f};

  for (int cbeg = beg; cbeg < end; cbeg += CHUNK) {
    const int cnum = (cbeg + CHUNK < end) ? CHUNK : (end - cbeg);
    if (tid < BUSERS) cnt[tid] = 0;
    __syncthreads();
    for (int i = tid; i < cnum; i += 256) {
      const int2 e = sedge[cbeg + i];
      eraw[i] = e;
      atomicAdd(&cnt[((unsigned int)e.x) >> 16], 1);
    }
    __syncthreads();
    if (tid < BUSERS) incl[tid] = cnt[tid];
    __syncthreads();
    for (int s = 1; s < BUSERS; s <<= 1) {
      int y = 0;
      if (tid < BUSERS && tid >= s) y = incl[tid - s];
      __syncthreads();
      if (tid < BUSERS) incl[tid] += y;
      __syncthreads();
    }
    if (tid < BUSERS) cnt[tid] = incl[tid] - cnt[tid];
    __syncthreads();
    for (int i = tid; i < cnum; i += 256) {
      const int2 e = eraw[i];
      const int pos = atomicAdd(&cnt[((unsigned int)e.x) >> 16], 1);
      esort[pos] = e;
    }
    __syncthreads();
    // register accumulate: half-wave per user, 8-wide MLP
#pragma unroll
    for (int k = 0; k < 8; ++k) {
      const int ul = hw * 8 + k;
      const int s = (ul == 0) ? 0 : incl[ul - 1];
      const int t = incl[ul];
      int j = s;
      for (; j + 7 < t; j += 8) {
        int2 e[8];
        uint2 p[8];
#pragma unroll
        for (int q = 0; q < 8; ++q) e[q] = esort[j + q];
#pragma unroll
        for (int q = 0; q < 8; ++q)
          p[q] = Pb2[(size_t)(e[q].x & 0xffff) * 32 + lane];
#pragma unroll
        for (int q = 0; q < 8; ++q) {
          const float v = __int_as_float(e[q].y);
          acc[k].x += v * __uint_as_float(p[q].x << 16);
          acc[k].y += v * __uint_as_float(p[q].x & 0xffff0000u);
          acc[k].z += v * __uint_as_float(p[q].y << 16);
          acc[k].w += v * __uint_as_float(p[q].y & 0xffff0000u);
        }
      }
      for (; j < t; ++j) {
        const int2 e0 = esort[j];
        const uint2 p0 = Pb2[(size_t)(e0.x & 0xffff) * 32 + lane];
        const float v0 = __int_as_float(e0.y);
        acc[k].x += v0 * __uint_as_float(p0.x << 16);
        acc[k].y += v0 * __uint_as_float(p0.x & 0xffff0000u);
        acc[k].z += v0 * __uint_as_float(p0.y << 16);
        acc[k].w += v0 * __uint_as_float(p0.y & 0xffff0000u);
      }
    }
    __syncthreads();  // protect LDS before next chunk
  }

  // epilogue: scale by nj, full-row coalesced float4 stores
#pragma unroll
  for (int k = 0; k < 8; ++k) {
    const int u = u0 + hw * 8 + k;
    if (u < n_users) {
      const float s = nj[u];
      float4 a = acc[k];
      a.x *= s; a.y *= s; a.z *= s; a.w *= s;
      *reinterpret_cast<float4*>(out + (size_t)u * D + lane * 4) = a;
    }
  }
}

extern "C" void kernel_launch(void* const* d_in, const int* in_sizes, int n_in,
                              void* d_out, int out_size, void* d_ws,
                              size_t ws_size, hipStream_t stream) {
  const float* item_emb = (const float*)d_in[0];  // [n_items, 128]
  const float* user_nj  = (const float*)d_in[1];  // [n_users, 1]
  const float* weight   = (const float*)d_in[2];  // [128, 128]
  const float* adj_vals = (const float*)d_in[3];  // [E]
  const int*   adj_rows = (const int*)d_in[4];    // [E]
  const int*   adj_cols = (const int*)d_in[5];    // [E]

  const int n_items = in_sizes[0] / D;
  const int n_users = in_sizes[1];
  const int n_edges = in_sizes[3];
  float* out = (float*)d_out;

  const int nbuck = (n_users + BUSERS - 1) >> BSHIFT;  // 1563
  const int npw = (n_items + MROWS - 1) / MROWS;       // 782
  const int epb = (n_edges + NBLK - 1) / NBLK;         // 6250
  const int n_scan = nbuck * NBLK;                     // 400128
  const int nb_scan = (n_scan + 1023) / 1024;          // 391

  // ---- workspace layout (256B-aligned) ----
  auto align256 = [](size_t x) { return (x + 255) & ~(size_t)255; };
  char* ws = (char*)d_ws;
  size_t off = 0;
  unsigned short* Pb = (unsigned short*)(ws + off);
  off = align256(off + (size_t)n_items * D * 2);  // 12.8 MB
  int* bcount = (int*)(ws + off);  off = align256(off + (size_t)n_scan * 4);
  int* base = (int*)(ws + off);    off = align256(off + (size_t)n_scan * 4);
  int2* sedge = (int2*)(ws + off); off = align256(off + (size_t)n_edges * 8);
  int* carry = (int*)(ws + off);   off = align256(off + (size_t)nb_scan * 4);
  int* flag = (int*)(ws + off);    off = align256(off + (size_t)nb_scan * 4);

  // 0) zero the scan flags (small)
  hipMemsetAsync(flag, 0, (size_t)nb_scan * 4, stream);

  // 1) fused: pw GEMM (blocks [0,npw)) || bucket histograms ([npw, npw+NBLK))
  pw_hist_kernel<<<npw + NBLK, 256, 0, stream>>>(
      item_emb, weight, Pb, n_items, npw, adj_rows, bcount, n_edges, epb,
      nbuck);

  // 2) single-launch chained exclusive scan of bcount -> base
  chainscan_kernel<<<nb_scan, 1024, 0, stream>>>(bcount, base, carry, flag,
                                                 n_scan);

  // 3) scatter edges into bucket-sorted order (no global atomics)
  scatter2_kernel<<<NBLK, 256, 0, stream>>>(adj_rows, adj_cols, adj_vals, base,
                                            sedge, n_edges, epb, nbuck);

  // 4) per-bucket LDS counting-sort + register gather + nj scale + store
  bucket_gather_kernel<<<nbuck, 256, 0, stream>>>(
      reinterpret_cast<const uint2*>(Pb), base, sedge, user_nj, out,
      n_users, n_edges, nbuck);
}

// Round 13
// 146.135 us; speedup vs baseline: 17.4093x; 17.4093x over previous
//
#include <hip/hip_runtime.h>
#include <hip/hip_bf16.h>

#define D 128        // EMBED == LAYER == 128
#define BSHIFT 6     // 64 users per bucket
#define BUSERS (1 << BSHIFT)
#define NBLK 256     // blocks for hist/scatter passes
#define CHUNK 1280   // edges staged per bucket-chunk (avg bucket ~1024)
#define MROWS 64     // pw: item rows per block

typedef __attribute__((ext_vector_type(8))) short bf16x8;
typedef __attribute__((ext_vector_type(4))) float f32x4;

// round-to-nearest f32 -> bf16 bits
__device__ __forceinline__ unsigned int bf16rn(float f) {
  unsigned int u = __float_as_uint(f);
  return (u + 0x7fffu + ((u >> 16) & 1u)) >> 16;
}

// ---------------------------------------------------------------------------
// Kernel 1 (fused): blocks [0, npw) run the MFMA pw GEMM; blocks [npw,
// npw+NBLK) run the bucket histogram. Overlaps compute-heavy pw with
// BW-heavy hist and saves a launch gap. Shared LDS arena (48 KB).
// ---------------------------------------------------------------------------
__global__ __launch_bounds__(256) void pw_hist_kernel(
    const float* __restrict__ emb, const float* __restrict__ W,
    unsigned short* __restrict__ Pb, int n_items, int npw,
    const int* __restrict__ rows, int* __restrict__ bcount, int n_edges,
    int epb, int nbuck) {
  __shared__ __align__(16) char smem[49152];
  const int tid = threadIdx.x;

  if ((int)blockIdx.x < npw) {
    // ---------------- pw: P = item_emb @ W (MFMA bf16, verified r10) -------
    unsigned short* Wt = (unsigned short*)smem;            // 32 KB swizzled
    unsigned short* At = (unsigned short*)(smem + 32768);  // 16 KB swizzled
    const int m0 = blockIdx.x * MROWS;

    for (int i = tid; i < 128 * 128; i += 256) {
      const int k = i >> 7, c = i & 127;
      const unsigned short v = (unsigned short)bf16rn(W[i]);
      const int boff = c * 256 + ((2 * k) ^ ((c & 7) << 4));
      *reinterpret_cast<unsigned short*>(reinterpret_cast<char*>(Wt) + boff) = v;
    }
    for (int i = tid; i < MROWS * 128; i += 256) {
      const int r = i >> 7, k = i & 127;
      const int gr = m0 + r;
      const float f = (gr < n_items) ? emb[(size_t)gr * 128 + k] : 0.f;
      const unsigned short v = (unsigned short)bf16rn(f);
      const int boff = r * 256 + ((2 * k) ^ ((r & 7) << 4));
      *reinterpret_cast<unsigned short*>(reinterpret_cast<char*>(At) + boff) = v;
    }
    __syncthreads();

    const int w = tid >> 6;
    const int lane = tid & 63;
    const int lr = lane & 15;
    const int lg = lane >> 4;

    bf16x8 a[4];
    {
      const int rloc = w * 16 + lr;
#pragma unroll
      for (int ks = 0; ks < 4; ++ks) {
        const int boff = rloc * 256 + (((ks * 64) + lg * 16) ^ ((lr & 7) << 4));
        a[ks] = *reinterpret_cast<const bf16x8*>(
            reinterpret_cast<const char*>(At) + boff);
      }
    }

    f32x4 acc[8];
#pragma unroll
    for (int cs = 0; cs < 8; ++cs) acc[cs] = {0.f, 0.f, 0.f, 0.f};

#pragma unroll
    for (int cs = 0; cs < 8; ++cs) {
      const int c = cs * 16 + lr;
#pragma unroll
      for (int ks = 0; ks < 4; ++ks) {
        const int boff = c * 256 + (((ks * 64) + lg * 16) ^ ((lr & 7) << 4));
        const bf16x8 b = *reinterpret_cast<const bf16x8*>(
            reinterpret_cast<const char*>(Wt) + boff);
        acc[cs] = __builtin_amdgcn_mfma_f32_16x16x32_bf16(a[ks], b, acc[cs],
                                                          0, 0, 0);
      }
    }

#pragma unroll
    for (int cs = 0; cs < 8; ++cs) {
      const int c = cs * 16 + lr;
#pragma unroll
      for (int reg = 0; reg < 4; ++reg) {
        const int r = m0 + w * 16 + lg * 4 + reg;
        if (r < n_items)
          Pb[(size_t)r * 128 + c] = (unsigned short)bf16rn(acc[cs][reg]);
      }
    }
  } else {
    // ---------------- hist: per-block bucket histogram ---------------------
    int* h = (int*)smem;
    const int hb = blockIdx.x - npw;
    for (int b = tid; b < nbuck; b += 256) h[b] = 0;
    __syncthreads();
    const int e0 = hb * epb;
    const int e1 = (e0 + epb < n_edges) ? e0 + epb : n_edges;
    for (int e = e0 + tid; e < e1; e += 256)
      atomicAdd(&h[rows[e] >> BSHIFT], 1);
    __syncthreads();
    for (int b = tid; b < nbuck; b += 256)
      bcount[(size_t)b * NBLK + hb] = h[b];
  }
}

// ---------------------------------------------------------------------------
// 3-kernel exclusive scan over bcount (nbuck*NBLK entries) -> base.
// No inter-block communication (round-10-proven).
// ---------------------------------------------------------------------------
__global__ __launch_bounds__(1024) void blocksum_kernel(
    const int* __restrict__ in, int* __restrict__ partials, int n) {
  __shared__ int lds[1024];
  const int tid = threadIdx.x;
  const int i = blockIdx.x * 1024 + tid;
  lds[tid] = (i < n) ? in[i] : 0;
  __syncthreads();
  for (int s = 512; s > 0; s >>= 1) {
    if (tid < s) lds[tid] += lds[tid + s];
    __syncthreads();
  }
  if (tid == 0) partials[blockIdx.x] = lds[0];
}

__global__ __launch_bounds__(1024) void scanpart_kernel(
    const int* __restrict__ partials, int* __restrict__ blockoff, int nb) {
  __shared__ int lds[1024];
  const int tid = threadIdx.x;
  const int x = (tid < nb) ? partials[tid] : 0;
  lds[tid] = x;
  __syncthreads();
  for (int s = 1; s < 1024; s <<= 1) {
    const int y = (tid >= s) ? lds[tid - s] : 0;
    __syncthreads();
    lds[tid] += y;
    __syncthreads();
  }
  if (tid < nb) blockoff[tid] = lds[tid] - x;
}

__global__ __launch_bounds__(1024) void localscan_kernel(
    const int* __restrict__ in, const int* __restrict__ blockoff,
    int* __restrict__ base, int n) {
  __shared__ int lds[1024];
  const int tid = threadIdx.x;
  const int i = blockIdx.x * 1024 + tid;
  const int x = (i < n) ? in[i] : 0;
  lds[tid] = x;
  __syncthreads();
  for (int s = 1; s < 1024; s <<= 1) {
    const int y = (tid >= s) ? lds[tid - s] : 0;
    __syncthreads();
    lds[tid] += y;
    __syncthreads();
  }
  if (i < n) base[i] = blockoff[blockIdx.x] + lds[tid] - x;
}

// ---------------------------------------------------------------------------
// Kernel 3: scatter pass — LDS cursors seeded by scanned base.
// ---------------------------------------------------------------------------
__global__ __launch_bounds__(256) void scatter2_kernel(
    const int* __restrict__ rows, const int* __restrict__ cols,
    const float* __restrict__ vals, const int* __restrict__ base,
    int2* __restrict__ sedge, int n_edges, int epb, int nbuck) {
  __shared__ int cur[1600];
  const int tid = threadIdx.x;
  for (int b = tid; b < nbuck; b += 256)
    cur[b] = base[(size_t)b * NBLK + blockIdx.x];
  __syncthreads();
  const int e0 = blockIdx.x * epb;
  const int e1 = (e0 + epb < n_edges) ? e0 + epb : n_edges;
  for (int e = e0 + tid; e < e1; e += 256) {
    const int r = rows[e];
    const int pos = atomicAdd(&cur[r >> BSHIFT], 1);
    sedge[pos] =
        make_int2(((r & (BUSERS - 1)) << 16) | cols[e], __float_as_int(vals[e]));
  }
}

// ---------------------------------------------------------------------------
// Kernel 4: per-bucket LDS counting-sort + register accumulation.
// 256 threads = 8 half-waves x 8 users; 32 lanes own uint2 (4 bf16 cols).
// ---------------------------------------------------------------------------
__global__ __launch_bounds__(256) void bucket_gather_kernel(
    const uint2* __restrict__ Pb2,  // bf16 quads, 32 uint2 per row
    const int* __restrict__ base, const int2* __restrict__ sedge,
    const float* __restrict__ nj, float* __restrict__ out, int n_users,
    int n_edges, int nbuck) {
  __shared__ int2 eraw[CHUNK];    // 10 KB
  __shared__ int2 esort[CHUNK];   // 10 KB
  __shared__ int cnt[BUSERS];
  __shared__ int incl[BUSERS];

  const int tid = threadIdx.x;
  const int b = blockIdx.x;
  const int u0 = b << BSHIFT;
  const int hw = tid >> 5;        // half-wave 0..7
  const int lane = tid & 31;

  const int beg = base[(size_t)b * NBLK];
  const int end = (b + 1 < nbuck) ? base[(size_t)(b + 1) * NBLK] : n_edges;

  float4 acc[8];
#pragma unroll
  for (int k = 0; k < 8; ++k) acc[k] = {0.f, 0.f, 0.f, 0.f};

  for (int cbeg = beg; cbeg < end; cbeg += CHUNK) {
    const int cnum = (cbeg + CHUNK < end) ? CHUNK : (end - cbeg);
    if (tid < BUSERS) cnt[tid] = 0;
    __syncthreads();
    for (int i = tid; i < cnum; i += 256) {
      const int2 e = sedge[cbeg + i];
      eraw[i] = e;
      atomicAdd(&cnt[((unsigned int)e.x) >> 16], 1);
    }
    __syncthreads();
    if (tid < BUSERS) incl[tid] = cnt[tid];
    __syncthreads();
    for (int s = 1; s < BUSERS; s <<= 1) {
      int y = 0;
      if (tid < BUSERS && tid >= s) y = incl[tid - s];
      __syncthreads();
      if (tid < BUSERS) incl[tid] += y;
      __syncthreads();
    }
    if (tid < BUSERS) cnt[tid] = incl[tid] - cnt[tid];
    __syncthreads();
    for (int i = tid; i < cnum; i += 256) {
      const int2 e = eraw[i];
      const int pos = atomicAdd(&cnt[((unsigned int)e.x) >> 16], 1);
      esort[pos] = e;
    }
    __syncthreads();
    // register accumulate: half-wave per user, 8-wide MLP
#pragma unroll
    for (int k = 0; k < 8; ++k) {
      const int ul = hw * 8 + k;
      const int s = (ul == 0) ? 0 : incl[ul - 1];
      const int t = incl[ul];
      int j = s;
      for (; j + 7 < t; j += 8) {
        int2 e[8];
        uint2 p[8];
#pragma unroll
        for (int q = 0; q < 8; ++q) e[q] = esort[j + q];
#pragma unroll
        for (int q = 0; q < 8; ++q)
          p[q] = Pb2[(size_t)(e[q].x & 0xffff) * 32 + lane];
#pragma unroll
        for (int q = 0; q < 8; ++q) {
          const float v = __int_as_float(e[q].y);
          acc[k].x += v * __uint_as_float(p[q].x << 16);
          acc[k].y += v * __uint_as_float(p[q].x & 0xffff0000u);
          acc[k].z += v * __uint_as_float(p[q].y << 16);
          acc[k].w += v * __uint_as_float(p[q].y & 0xffff0000u);
        }
      }
      for (; j < t; ++j) {
        const int2 e0 = esort[j];
        const uint2 p0 = Pb2[(size_t)(e0.x & 0xffff) * 32 + lane];
        const float v0 = __int_as_float(e0.y);
        acc[k].x += v0 * __uint_as_float(p0.x << 16);
        acc[k].y += v0 * __uint_as_float(p0.x & 0xffff0000u);
        acc[k].z += v0 * __uint_as_float(p0.y << 16);
        acc[k].w += v0 * __uint_as_float(p0.y & 0xffff0000u);
      }
    }
    __syncthreads();  // protect LDS before next chunk
  }

  // epilogue: scale by nj, full-row coalesced float4 stores
#pragma unroll
  for (int k = 0; k < 8; ++k) {
    const int u = u0 + hw * 8 + k;
    if (u < n_users) {
      const float s = nj[u];
      float4 a = acc[k];
      a.x *= s; a.y *= s; a.z *= s; a.w *= s;
      *reinterpret_cast<float4*>(out + (size_t)u * D + lane * 4) = a;
    }
  }
}

extern "C" void kernel_launch(void* const* d_in, const int* in_sizes, int n_in,
                              void* d_out, int out_size, void* d_ws,
                              size_t ws_size, hipStream_t stream) {
  const float* item_emb = (const float*)d_in[0];  // [n_items, 128]
  const float* user_nj  = (const float*)d_in[1];  // [n_users, 1]
  const float* weight   = (const float*)d_in[2];  // [128, 128]
  const float* adj_vals = (const float*)d_in[3];  // [E]
  const int*   adj_rows = (const int*)d_in[4];    // [E]
  const int*   adj_cols = (const int*)d_in[5];    // [E]

  const int n_items = in_sizes[0] / D;
  const int n_users = in_sizes[1];
  const int n_edges = in_sizes[3];
  float* out = (float*)d_out;

  const int nbuck = (n_users + BUSERS - 1) >> BSHIFT;  // 1563
  const int npw = (n_items + MROWS - 1) / MROWS;       // 782
  const int epb = (n_edges + NBLK - 1) / NBLK;         // 6250
  const int n_scan = nbuck * NBLK;                     // 400128
  const int nb_scan = (n_scan + 1023) / 1024;          // 391

  // ---- workspace layout (256B-aligned) ----
  auto align256 = [](size_t x) { return (x + 255) & ~(size_t)255; };
  char* ws = (char*)d_ws;
  size_t off = 0;
  unsigned short* Pb = (unsigned short*)(ws + off);
  off = align256(off + (size_t)n_items * D * 2);  // 12.8 MB
  int* bcount = (int*)(ws + off);  off = align256(off + (size_t)n_scan * 4);
  int* base = (int*)(ws + off);    off = align256(off + (size_t)n_scan * 4);
  int2* sedge = (int2*)(ws + off); off = align256(off + (size_t)n_edges * 8);
  int* partials = (int*)(ws + off); off = align256(off + (size_t)nb_scan * 4);
  int* blockoff = (int*)(ws + off); off = align256(off + (size_t)nb_scan * 4);

  // 1) fused: pw GEMM (blocks [0,npw)) || bucket histograms ([npw, npw+NBLK))
  pw_hist_kernel<<<npw + NBLK, 256, 0, stream>>>(
      item_emb, weight, Pb, n_items, npw, adj_rows, bcount, n_edges, epb,
      nbuck);

  // 2) 3-kernel exclusive scan of bcount -> base (no inter-block comms)
  blocksum_kernel<<<nb_scan, 1024, 0, stream>>>(bcount, partials, n_scan);
  scanpart_kernel<<<1, 1024, 0, stream>>>(partials, blockoff, nb_scan);
  localscan_kernel<<<nb_scan, 1024, 0, stream>>>(bcount, blockoff, base,
                                                 n_scan);

  // 3) scatter edges into bucket-sorted order (no global atomics)
  scatter2_kernel<<<NBLK, 256, 0, stream>>>(adj_rows, adj_cols, adj_vals, base,
                                            sedge, n_edges, epb, nbuck);

  // 4) per-bucket LDS counting-sort + register gather + nj scale + store
  bucket_gather_kernel<<<nbuck, 256, 0, stream>>>(
      reinterpret_cast<const uint2*>(Pb), base, sedge, user_nj, out,
      n_users, n_edges, nbuck);
}